// Round 1
// 1578.776 us; speedup vs baseline: 1.4954x; 1.4954x over previous
//
#include <hip/hip_runtime.h>
#include <hip/hip_bf16.h>

#define N_NODES 100000
#define T_STEPS 10
#define F_DIM   64
#define E_EDGES 1600000
#define ED_DIM  8
#define H_DIM   128
#define B_BATCH 2048
#define C_CLS   2
#define TF      640      // T*F
#define K_IN    136      // F (self) + F (agg-x) + ED (agg-edge)
#define G4H     512      // 4*H
#define XROW    168      // stats LDS row pitch in bf16 elements
#define PBLK    98       // scan blocks: 98*1024 >= 100000
#define LPITCH  136      // lstm LDS row pitch in bf16 (136*2B=272B=17 dw4: bank-conflict-free)

typedef __attribute__((ext_vector_type(8))) short short8;
typedef __attribute__((ext_vector_type(4))) float f32x4;

__device__ __forceinline__ unsigned short fbs(float f) {
    __hip_bfloat16 h = __float2bfloat16(f);
    return *(unsigned short*)&h;
}
__device__ __forceinline__ float bs2f(unsigned short u) {
    unsigned int v = ((unsigned int)u) << 16;
    return __uint_as_float(v);
}
__device__ __forceinline__ unsigned int pack2(float lo, float hi) {
    return (unsigned int)fbs(lo) | ((unsigned int)fbs(hi) << 16);
}
__device__ __forceinline__ float fsig(float x) {
    return 1.0f / (1.0f + __expf(-x));
}
__device__ __forceinline__ float ftanh(float x) {
    // tanh(x) = 1 - 2/(exp(2x)+1); exp overflow -> inf -> 1, underflow -> 0 -> -1
    float e = __expf(2.0f * x);
    return 1.0f - 2.0f / (e + 1.0f);
}

// ---- workspace layout (offsets in floats) ----
#define WS_DEG      0            // N ints
#define WS_ROWPTR   100096       // N+1 ints
#define WS_CURSOR   200192       // N ints
#define WS_INV      300288       // N floats
#define WS_AGGE     400384       // N*8 fp32 (scaled in place; focal reads)
#define WS_SUMS     1200384      // 10*256
#define WS_ZEND     1202944      // end of single upfront zero region
#define WS_CSRSRC   1202944      // E ints
#define WS_AGGXB    2802944      // N*64 bf16 (3.2M float slots)
#define WS_AGGEB    6002944      // N*8 bf16
#define WS_HSEQB    6402944      // T*B*H bf16
#define WS_HN       7713664      // B*H fp32
#define WS_WB       7975808      // 20480 bf16 (stats W, MFMA B-layout)
#define WS_WL       7986048      // 131072 bf16 (LSTM W, permuted MFMA B-layout)
#define WS_PART     8051584      // 98 ints
#define WS_BOFF     8051712      // 98 ints
#define WS_XB       8051840      // N*TF bf16 (32M float slots)

// ---------------- x -> bf16 cast (once) ----------------
__global__ __launch_bounds__(256) void k_xcast(const float* __restrict__ x,
                                               unsigned short* __restrict__ xb) {
    int i = blockIdx.x * blockDim.x + threadIdx.x;   // over N*TF/8 = 8,000,000
    const float4* x4 = (const float4*)x;
    float4 a = x4[2 * i], b = x4[2 * i + 1];
    uint4 o;
    o.x = pack2(a.x, a.y);
    o.y = pack2(a.z, a.w);
    o.z = pack2(b.x, b.y);
    o.w = pack2(b.z, b.w);
    ((uint4*)xb)[i] = o;
}

// ---------------- degree ----------------
__global__ void k_deg(const int* __restrict__ ei, int* __restrict__ deg) {
    int e = blockIdx.x * blockDim.x + threadIdx.x;
    if (e < E_EDGES) atomicAdd(&deg[ei[E_EDGES + e]], 1);
}

// ---------------- parallel scan: block partials ----------------
__global__ __launch_bounds__(1024) void k_part(const int* __restrict__ deg,
                                               int* __restrict__ part) {
    __shared__ int red[1024];
    int gid = blockIdx.x * 1024 + threadIdx.x;
    red[threadIdx.x] = (gid < N_NODES) ? deg[gid] : 0;
    __syncthreads();
    for (int off = 512; off > 0; off >>= 1) {
        if (threadIdx.x < off) red[threadIdx.x] += red[threadIdx.x + off];
        __syncthreads();
    }
    if (threadIdx.x == 0) part[blockIdx.x] = red[0];
}

__global__ __launch_bounds__(128) void k_scanpart(const int* __restrict__ part,
        int* __restrict__ boff, int* __restrict__ rowptr) {
    __shared__ int buf[128];
    int li = threadIdx.x;
    int v = (li < PBLK) ? part[li] : 0;
    buf[li] = v;
    __syncthreads();
    for (int off = 1; off < 128; off <<= 1) {
        int u = (li >= off) ? buf[li - off] : 0;
        __syncthreads();
        buf[li] += u;
        __syncthreads();
    }
    if (li < PBLK) boff[li] = buf[li] - v;
    if (li == 0) rowptr[N_NODES] = E_EDGES;
}

__global__ __launch_bounds__(1024) void k_rowfill(const int* __restrict__ deg,
        const int* __restrict__ boff, int* __restrict__ rowptr,
        int* __restrict__ cursor, float* __restrict__ inv) {
    __shared__ int buf[1024];
    int li = threadIdx.x;
    int gid = blockIdx.x * 1024 + li;
    int d = (gid < N_NODES) ? deg[gid] : 0;
    buf[li] = d;
    __syncthreads();
    for (int off = 1; off < 1024; off <<= 1) {
        int u = (li >= off) ? buf[li - off] : 0;
        __syncthreads();
        buf[li] += u;
        __syncthreads();
    }
    if (gid < N_NODES) {
        int excl = boff[blockIdx.x] + buf[li] - d;
        rowptr[gid] = excl;
        cursor[gid] = excl;
        inv[gid] = 1.0f / (float)(d > 1 ? d : 1);
    }
}

// ---------------- CSR fill ----------------
__global__ void k_fill(const int* __restrict__ ei, int* __restrict__ cursor,
                       int* __restrict__ csr_src) {
    int e = blockIdx.x * blockDim.x + threadIdx.x;
    if (e < E_EDGES) {
        int dst = ei[E_EDGES + e];
        int pos = atomicAdd(&cursor[dst], 1);
        csr_src[pos] = ei[e];
    }
}

// ---------------- edge-attr aggregation (t-invariant) ----------------
__global__ void k_agge(const int* __restrict__ ei, const float* __restrict__ ea,
                       float* __restrict__ agge) {
    int i = blockIdx.x * blockDim.x + threadIdx.x;   // over E*8
    if (i < E_EDGES * ED_DIM) {
        int e = i >> 3, j = i & 7;
        int dst = ei[E_EDGES + e];
        atomicAdd(&agge[dst * ED_DIM + j], ea[i]);
    }
}

__global__ void k_scale_agge(float* __restrict__ agge, const float* __restrict__ inv,
                             unsigned short* __restrict__ aggeb) {
    int i = blockIdx.x * blockDim.x + threadIdx.x;
    if (i < N_NODES * ED_DIM) {
        float v = agge[i] * inv[i >> 3];
        agge[i] = v;
        aggeb[i] = fbs(v);
    }
}

// ---------------- pack stats weights into MFMA B-frag layout, bf16 ----------------
__global__ void k_wprep(const float* __restrict__ wself, const float* __restrict__ wmsg,
                        unsigned short* __restrict__ wB) {
    int i = blockIdx.x * blockDim.x + threadIdx.x;   // over 5*4096 = 20480
    if (i < 20480) {
        int j = i & 7, q = (i >> 3) & 3, n = (i >> 5) & 127, kt = i >> 12;
        int k = kt * 32 + q * 8 + j;
        float v = 0.f;
        if (k < 64)       v = wself[k * 128 + n];
        else if (k < 136) v = wmsg[(k - 64) * 128 + n];
        wB[i] = fbs(v);
    }
}

// ---------------- pack LSTM weights, gate-permuted MFMA B-frag layout, bf16 ----------------
// col' = hsub*64 + gate*16 + hlo  (wave hsub owns full i,f,g,o for h=hsub*16+hlo)
__global__ void k_wlstm(const float* __restrict__ wih, const float* __restrict__ whh,
                        unsigned short* __restrict__ wL) {
    int i = blockIdx.x * blockDim.x + threadIdx.x;   // over 8*512*32 = 131072
    if (i < 131072) {
        int j8 = i & 7, q = (i >> 3) & 3, np = (i >> 5) & 511, kt = i >> 14;
        int k = kt * 32 + q * 8 + j8;
        int hsub = np >> 6, gate = (np >> 4) & 3, hlo = np & 15;
        int j = gate * 128 + hsub * 16 + hlo;
        float v = (k < 128) ? wih[j * H_DIM + k] : whh[j * H_DIM + (k - 128)];
        wL[i] = fbs(v);
    }
}

// ---------------- per-t CSR gather (bf16): aggxb[n] = inv[n]*sum x_t[src] ----------------
// one wave per node; half-wave per edge, lane = 2 features (uint = 2 bf16)
// 8-edge unroll: 4 independent 128B loads in flight per half-wave (MLP)
__global__ __launch_bounds__(256) void k_gather(const unsigned short* __restrict__ xb,
        const int* __restrict__ rowptr, const int* __restrict__ csr_src,
        const float* __restrict__ inv, unsigned short* __restrict__ aggxb, int t) {
    int node = blockIdx.x * 4 + (threadIdx.x >> 6);
    int lane = threadIdx.x & 63;
    int half = lane >> 5, li = lane & 31;
    int beg = rowptr[node], end = rowptr[node + 1];
    const unsigned short* xt = xb + t * F_DIM + 2 * li;
    float a0 = 0.f, a1 = 0.f;
    int e = beg;
    for (; e + 7 < end; e += 8) {
        int s0 = csr_src[e + half];
        int s1 = csr_src[e + 2 + half];
        int s2 = csr_src[e + 4 + half];
        int s3 = csr_src[e + 6 + half];
        unsigned int u0 = *(const unsigned int*)&xt[(size_t)s0 * TF];
        unsigned int u1 = *(const unsigned int*)&xt[(size_t)s1 * TF];
        unsigned int u2 = *(const unsigned int*)&xt[(size_t)s2 * TF];
        unsigned int u3 = *(const unsigned int*)&xt[(size_t)s3 * TF];
        a0 += __uint_as_float(u0 << 16) + __uint_as_float(u1 << 16)
            + __uint_as_float(u2 << 16) + __uint_as_float(u3 << 16);
        a1 += __uint_as_float(u0 & 0xffff0000u) + __uint_as_float(u1 & 0xffff0000u)
            + __uint_as_float(u2 & 0xffff0000u) + __uint_as_float(u3 & 0xffff0000u);
    }
    if (e + 3 < end) {
        int s0 = csr_src[e + half], s1 = csr_src[e + 2 + half];
        unsigned int u0 = *(const unsigned int*)&xt[(size_t)s0 * TF];
        unsigned int u1 = *(const unsigned int*)&xt[(size_t)s1 * TF];
        a0 += __uint_as_float(u0 << 16) + __uint_as_float(u1 << 16);
        a1 += __uint_as_float(u0 & 0xffff0000u) + __uint_as_float(u1 & 0xffff0000u);
        e += 4;
    }
    if (e + 1 < end) {
        int s = csr_src[e + half];
        unsigned int u = *(const unsigned int*)&xt[(size_t)s * TF];
        a0 += __uint_as_float(u << 16);
        a1 += __uint_as_float(u & 0xffff0000u);
        e += 2;
    }
    if (half == 0 && e < end) {
        int s = csr_src[e];
        unsigned int u = *(const unsigned int*)&xt[(size_t)s * TF];
        a0 += __uint_as_float(u << 16);
        a1 += __uint_as_float(u & 0xffff0000u);
    }
    a0 += __shfl_xor(a0, 32, 64);
    a1 += __shfl_xor(a1, 32, 64);
    if (lane < 32) {
        float iv = inv[node];
        *(unsigned int*)&aggxb[node * F_DIM + 2 * li] = pack2(a0 * iv, a1 * iv);
    }
}

// ---------------- BN stats via bf16 MFMA: sum & sumsq of (xin @ W) ----------------
// grid-stride over 32-row tiles; cs/cq accumulate in registers across tiles;
// single atomic flush per block at the end (atomic count 800K -> 131K per t).
__global__ __launch_bounds__(256) void k_stats(const unsigned short* __restrict__ xb,
        const unsigned short* __restrict__ aggxb, const unsigned short* __restrict__ aggeb,
        const unsigned short* __restrict__ wB, float* __restrict__ sums, int t) {
    __shared__ __align__(16) unsigned short s_xa[32 * XROW];
    int tid  = threadIdx.x;
    int wave = tid >> 6, lane = tid & 63;
    int q = lane >> 4, m = lane & 15;
    int n0 = wave * 32;

    // hoist t-invariant B-fragments into registers (5 kt x 2 col-halves)
    short8 bf[5][2];
    #pragma unroll
    for (int kt = 0; kt < 5; kt++) {
        bf[kt][0] = *(const short8*)&wB[kt * 4096 + (n0 + m) * 32 + q * 8];
        bf[kt][1] = *(const short8*)&wB[kt * 4096 + (n0 + 16 + m) * 32 + q * 8];
    }

    float cs0 = 0.f, cq0 = 0.f, cs1 = 0.f, cq1 = 0.f;

    for (int tile = blockIdx.x; tile < N_NODES / 32; tile += gridDim.x) {
        int row0 = tile * 32;
        __syncthreads();   // previous tile's LDS reads done before restage
        // stage 32 rows x 160 (pad-zeroed) bf16 — pure uint4 copies, no conversion
        for (int i = tid; i < 32 * 20; i += 256) {
            int r = i / 20, qq = i - r * 20;
            int n = row0 + r;
            uint4 v = make_uint4(0, 0, 0, 0);
            if (qq < 8)        v = *(const uint4*)&xb[(size_t)n * TF + t * F_DIM + qq * 8];
            else if (qq < 16)  v = *(const uint4*)&aggxb[n * F_DIM + (qq - 8) * 8];
            else if (qq == 16) v = *(const uint4*)&aggeb[n * ED_DIM];
            *(uint4*)&s_xa[r * XROW + qq * 8] = v;
        }
        __syncthreads();

        f32x4 a00 = {0.f,0.f,0.f,0.f}, a01 = a00, a10 = a00, a11 = a00;
        #pragma unroll
        for (int kt = 0; kt < 5; kt++) {
            short8 af0 = *(const short8*)&s_xa[m * XROW + kt * 32 + q * 8];
            short8 af1 = *(const short8*)&s_xa[(16 + m) * XROW + kt * 32 + q * 8];
            a00 = __builtin_amdgcn_mfma_f32_16x16x32_bf16(af0, bf[kt][0], a00, 0, 0, 0);
            a10 = __builtin_amdgcn_mfma_f32_16x16x32_bf16(af1, bf[kt][0], a10, 0, 0, 0);
            a01 = __builtin_amdgcn_mfma_f32_16x16x32_bf16(af0, bf[kt][1], a01, 0, 0, 0);
            a11 = __builtin_amdgcn_mfma_f32_16x16x32_bf16(af1, bf[kt][1], a11, 0, 0, 0);
        }
        #pragma unroll
        for (int g = 0; g < 4; g++) {
            float v0 = a00[g], v1 = a10[g];
            cs0 += v0 + v1;
            cq0 += v0 * v0 + v1 * v1;
            float w0 = a01[g], w1 = a11[g];
            cs1 += w0 + w1;
            cq1 += w0 * w0 + w1 * w1;
        }
    }

    // deferred cross-lane reduce + single flush
    cs0 += __shfl_xor(cs0, 16, 64); cq0 += __shfl_xor(cq0, 16, 64);
    cs0 += __shfl_xor(cs0, 32, 64); cq0 += __shfl_xor(cq0, 32, 64);
    cs1 += __shfl_xor(cs1, 16, 64); cq1 += __shfl_xor(cq1, 16, 64);
    cs1 += __shfl_xor(cs1, 32, 64); cq1 += __shfl_xor(cq1, 32, 64);
    if (lane < 16) {
        atomicAdd(&sums[n0 + m], cs0);
        atomicAdd(&sums[128 + n0 + m], cq0);
        atomicAdd(&sums[n0 + 16 + m], cs1);
        atomicAdd(&sums[128 + n0 + 16 + m], cq1);
    }
}

// ---------------- focal rows: hseqb[t,b,:] = bf16(relu(BN(xin[ptr[b]] @ W))) ----------------
__global__ __launch_bounds__(128) void k_focal(const float* __restrict__ x,
        const unsigned short* __restrict__ aggxb, const float* __restrict__ agge,
        const float* __restrict__ wself, const float* __restrict__ wmsg,
        const float* __restrict__ sums, const float* __restrict__ gamma,
        const float* __restrict__ beta, const int* __restrict__ ptr,
        unsigned short* __restrict__ hseqb, int t) {
    __shared__ float s_xin[K_IN];
    int b   = blockIdx.x;
    int n   = ptr[b];
    int tid = threadIdx.x;
    if (tid < K_IN - 64) {
        int k = 64 + tid;
        s_xin[k] = (k < 128) ? bs2f(aggxb[n * F_DIM + (k - 64)])
                             : agge[n * ED_DIM + (k - 128)];
    }
    {
        int k = tid & 63;
        s_xin[k] = x[(size_t)n * TF + t * F_DIM + k];
    }
    __syncthreads();
    int h = tid;
    float acc = 0.f;
    #pragma unroll 8
    for (int k = 0; k < F_DIM; k++) acc += s_xin[k] * wself[k * H_DIM + h];
    #pragma unroll 8
    for (int k = 0; k < 72; k++)    acc += s_xin[F_DIM + k] * wmsg[k * H_DIM + h];
    float mean = sums[h] * (1.0f / N_NODES);
    float var  = sums[H_DIM + h] * (1.0f / N_NODES) - mean * mean;
    var = fmaxf(var, 0.f);
    float istd = 1.0f / sqrtf(var + 1e-5f);
    float sc = gamma[h] * istd;
    float sh = beta[h] - mean * sc;
    float v = fmaxf(acc * sc + sh, 0.f);
    hseqb[(size_t)(t * B_BATCH + b) * H_DIM + h] = fbs(v);
}

// ---------------- persistent MFMA LSTM: all 10 steps in one kernel ----------------
// 128 blocks x 512 thr; block owns 16 rows; wave owns 64 gate-cols (full i,f,g,o
// for 16 h-dims); wL hoisted into 128 VGPRs (t-invariant); LDS pitch 136 bf16
// kills the 16-way bank conflict of the old [row][128] layout.
__global__ __launch_bounds__(512) void k_lstm_all(const unsigned short* __restrict__ hseqb,
        const unsigned short* __restrict__ wL, const float* __restrict__ bih,
        const float* __restrict__ bhh, float* __restrict__ hn) {
    __shared__ __align__(16) unsigned short s_hin[16 * LPITCH];
    __shared__ __align__(16) unsigned short s_h[16 * LPITCH];
    int tid = threadIdx.x, w = tid >> 6, lane = tid & 63;
    int q = lane >> 4, hlo = lane & 15;
    int row0 = blockIdx.x * 16;
    for (int i = tid; i < 16 * LPITCH / 8; i += 512)
        ((uint4*)s_h)[i] = make_uint4(0, 0, 0, 0);
    float c[4] = {0.f, 0.f, 0.f, 0.f};
    float bias[4];
    #pragma unroll
    for (int nt = 0; nt < 4; nt++) {
        int j = nt * 128 + w * 16 + hlo;
        bias[nt] = bih[j] + bhh[j];
    }
    // hoist all B-fragments: 8 kt x 4 gates x 16B = 128 VGPRs, loaded once
    short8 bfr[8][4];
    #pragma unroll
    for (int kt = 0; kt < 8; kt++)
        #pragma unroll
        for (int nt = 0; nt < 4; nt++)
            bfr[kt][nt] = *(const short8*)&wL[((kt * 512) + (w * 64 + nt * 16 + hlo)) * 32 + q * 8];

    for (int t = 0; t < T_STEPS; t++) {
        // stage 16 rows x 128 bf16 (4 KB) into pitched LDS
        if (tid < 256) {
            int r = tid >> 4, cc = tid & 15;
            ((uint4*)&s_hin[r * LPITCH])[cc] =
                ((const uint4*)(hseqb + (size_t)(t * B_BATCH + row0 + r) * H_DIM))[cc];
        }
        __syncthreads();   // s_hin staged; prev-iter s_h writes visible
        f32x4 acc[4];
        #pragma unroll
        for (int nt = 0; nt < 4; nt++) acc[nt] = (f32x4){0.f, 0.f, 0.f, 0.f};
        #pragma unroll
        for (int kt = 0; kt < 8; kt++) {
            const unsigned short* abase = (kt < 4) ? s_hin : s_h;
            int ko = (kt & 3) * 32 + q * 8;
            short8 am = *(const short8*)&abase[hlo * LPITCH + ko];
            #pragma unroll
            for (int nt = 0; nt < 4; nt++)
                acc[nt] = __builtin_amdgcn_mfma_f32_16x16x32_bf16(am, bfr[kt][nt], acc[nt], 0, 0, 0);
        }
        __syncthreads();   // all s_h reads done before overwrite
        #pragma unroll
        for (int r = 0; r < 4; r++) {
            float gi = acc[0][r] + bias[0];
            float gf = acc[1][r] + bias[1];
            float gg = acc[2][r] + bias[2];
            float go = acc[3][r] + bias[3];
            float si = fsig(gi);
            float sf = fsig(gf);
            float so = fsig(go);
            float tg = ftanh(gg);
            float cn = sf * c[r] + si * tg;
            c[r] = cn;
            float hv = so * ftanh(cn);
            int row = q * 4 + r;
            s_h[row * LPITCH + w * 16 + hlo] = fbs(hv);
            if (t == T_STEPS - 1)
                hn[(size_t)(row0 + row) * H_DIM + w * 16 + hlo] = hv;
        }
    }
}

// ---------------- classifier ----------------
__global__ void k_cls(const float* __restrict__ h, const float* __restrict__ wcls,
                      const float* __restrict__ bcls, float* __restrict__ out) {
    int i = blockIdx.x * blockDim.x + threadIdx.x;
    if (i < B_BATCH * C_CLS) {
        int b = i >> 1, cc = i & 1;
        float acc = bcls[cc];
        for (int k = 0; k < H_DIM; k++) acc += h[b * H_DIM + k] * wcls[k * C_CLS + cc];
        out[i] = acc;
    }
}

extern "C" void kernel_launch(void* const* d_in, const int* in_sizes, int n_in,
                              void* d_out, int out_size, void* d_ws, size_t ws_size,
                              hipStream_t stream) {
    const float* x     = (const float*)d_in[0];
    const int*   ei    = (const int*)d_in[1];
    const float* ea    = (const float*)d_in[2];
    const int*   ptr   = (const int*)d_in[3];
    const float* wmsg  = (const float*)d_in[4];
    const float* wself = (const float*)d_in[6];
    const float* gamma = (const float*)d_in[8];
    const float* beta  = (const float*)d_in[9];
    const float* wih   = (const float*)d_in[10];
    const float* whh   = (const float*)d_in[11];
    const float* bih   = (const float*)d_in[12];
    const float* bhh   = (const float*)d_in[13];
    const float* wcls  = (const float*)d_in[14];
    const float* bcls  = (const float*)d_in[15];
    float* out = (float*)d_out;

    float* ws = (float*)d_ws;
    int*            deg    = (int*)(ws + WS_DEG);
    int*            rowptr = (int*)(ws + WS_ROWPTR);
    int*            cursor = (int*)(ws + WS_CURSOR);
    float*          inv    = ws + WS_INV;
    float*          agge   = ws + WS_AGGE;
    float*          sums   = ws + WS_SUMS;
    int*            csrs   = (int*)(ws + WS_CSRSRC);
    unsigned short* aggxb  = (unsigned short*)(ws + WS_AGGXB);
    unsigned short* aggeb  = (unsigned short*)(ws + WS_AGGEB);
    unsigned short* hseqb  = (unsigned short*)(ws + WS_HSEQB);
    float*          hn     = ws + WS_HN;
    unsigned short* wB     = (unsigned short*)(ws + WS_WB);
    unsigned short* wL     = (unsigned short*)(ws + WS_WL);
    int*            part   = (int*)(ws + WS_PART);
    int*            boff   = (int*)(ws + WS_BOFF);
    unsigned short* xb     = (unsigned short*)(ws + WS_XB);

    hipMemsetAsync(ws, 0, (size_t)WS_ZEND * 4, stream);

    k_xcast<<<31250, 256, 0, stream>>>(x, xb);
    k_deg<<<(E_EDGES + 255) / 256, 256, 0, stream>>>(ei, deg);
    k_part<<<PBLK, 1024, 0, stream>>>(deg, part);
    k_scanpart<<<1, 128, 0, stream>>>(part, boff, rowptr);
    k_rowfill<<<PBLK, 1024, 0, stream>>>(deg, boff, rowptr, cursor, inv);
    k_agge<<<(E_EDGES * ED_DIM + 255) / 256, 256, 0, stream>>>(ei, ea, agge);
    k_scale_agge<<<(N_NODES * ED_DIM + 255) / 256, 256, 0, stream>>>(agge, inv, aggeb);
    k_fill<<<(E_EDGES + 255) / 256, 256, 0, stream>>>(ei, cursor, csrs);
    k_wprep<<<80, 256, 0, stream>>>(wself, wmsg, wB);
    k_wlstm<<<512, 256, 0, stream>>>(wih, whh, wL);

    for (int t = 0; t < T_STEPS; t++) {
        float* sums_t = sums + t * 256;
        k_gather<<<N_NODES / 4, 256, 0, stream>>>(xb, rowptr, csrs, inv, aggxb, t);
        k_stats<<<512, 256, 0, stream>>>(xb, aggxb, aggeb, wB, sums_t, t);
        k_focal<<<B_BATCH, 128, 0, stream>>>(x, aggxb, agge, wself, wmsg, sums_t,
                                             gamma, beta, ptr, hseqb, t);
    }
    k_lstm_all<<<B_BATCH / 16, 512, 0, stream>>>(hseqb, wL, bih, bhh, hn);
    k_cls<<<(B_BATCH * C_CLS + 255) / 256, 256, 0, stream>>>(hn, wcls, bcls, out);
}

// Round 2
// 1312.114 us; speedup vs baseline: 1.7993x; 1.2032x over previous
//
#include <hip/hip_runtime.h>
#include <hip/hip_bf16.h>

#define N_NODES 100000
#define T_STEPS 10
#define F_DIM   64
#define E_EDGES 1600000
#define ED_DIM  8
#define H_DIM   128
#define B_BATCH 2048
#define C_CLS   2
#define TF      640      // T*F
#define K_IN    136      // F (self) + F (agg-x) + ED (agg-edge)
#define G4H     512      // 4*H
#define XROW    168      // stats LDS row pitch in bf16 elements
#define PBLK    98       // scan blocks: 98*1024 >= 100000
#define LPITCH  136      // lstm LDS row pitch in bf16 (136*2B=272B: bank-conflict-free)

typedef __attribute__((ext_vector_type(8))) short short8;
typedef __attribute__((ext_vector_type(4))) float f32x4;

__device__ __forceinline__ unsigned short fbs(float f) {
    __hip_bfloat16 h = __float2bfloat16(f);
    return *(unsigned short*)&h;
}
__device__ __forceinline__ float bs2f(unsigned short u) {
    unsigned int v = ((unsigned int)u) << 16;
    return __uint_as_float(v);
}
__device__ __forceinline__ unsigned int pack2(float lo, float hi) {
    return (unsigned int)fbs(lo) | ((unsigned int)fbs(hi) << 16);
}
__device__ __forceinline__ float fsig(float x) {
    return 1.0f / (1.0f + __expf(-x));
}
__device__ __forceinline__ float ftanh(float x) {
    float e = __expf(2.0f * x);
    return 1.0f - 2.0f / (e + 1.0f);
}

// ---- workspace layout (offsets in floats; ws_size ~= 1 GB per harness fill) ----
#define WS_DEG      0            // N ints
#define WS_ROWPTR   100096       // N+1 ints
#define WS_CURSOR   200192       // N ints
#define WS_INV      300288       // N floats
#define WS_AGGE     400384       // N*8 fp32 (scaled in place; focal reads)
#define WS_SUMS     1200384      // 10*256
#define WS_ZEND     1202944      // end of single upfront zero region
#define WS_CSRSRC   1202944      // E ints
#define WS_AGGEB    6002944      // N*8 bf16
#define WS_HSEQB    6402944      // T*B*H bf16
#define WS_HN       7713664      // B*H fp32
#define WS_WB       7975808      // 20480 bf16 (stats W, MFMA B-layout)
#define WS_WL       7986048      // 131072 bf16 (LSTM W, permuted MFMA B-layout)
#define WS_PART     8051584      // 98 ints
#define WS_BOFF     8051712      // 98 ints
#define WS_XB       8051840      // N*TF bf16 (32M float slots) -> ends 40051840
#define WS_AGGXB    40051840     // N*TF bf16 (all-t aggregate, 32M float slots) -> ends 72051840 (~288 MB)

// ---------------- x -> bf16 cast (once) ----------------
__global__ __launch_bounds__(256) void k_xcast(const float* __restrict__ x,
                                               unsigned short* __restrict__ xb) {
    int i = blockIdx.x * blockDim.x + threadIdx.x;   // over N*TF/8 = 8,000,000
    const float4* x4 = (const float4*)x;
    float4 a = x4[2 * i], b = x4[2 * i + 1];
    uint4 o;
    o.x = pack2(a.x, a.y);
    o.y = pack2(a.z, a.w);
    o.z = pack2(b.x, b.y);
    o.w = pack2(b.z, b.w);
    ((uint4*)xb)[i] = o;
}

// ---------------- degree ----------------
__global__ void k_deg(const int* __restrict__ ei, int* __restrict__ deg) {
    int e = blockIdx.x * blockDim.x + threadIdx.x;
    if (e < E_EDGES) atomicAdd(&deg[ei[E_EDGES + e]], 1);
}

// ---------------- parallel scan: block partials ----------------
__global__ __launch_bounds__(1024) void k_part(const int* __restrict__ deg,
                                               int* __restrict__ part) {
    __shared__ int red[1024];
    int gid = blockIdx.x * 1024 + threadIdx.x;
    red[threadIdx.x] = (gid < N_NODES) ? deg[gid] : 0;
    __syncthreads();
    for (int off = 512; off > 0; off >>= 1) {
        if (threadIdx.x < off) red[threadIdx.x] += red[threadIdx.x + off];
        __syncthreads();
    }
    if (threadIdx.x == 0) part[blockIdx.x] = red[0];
}

__global__ __launch_bounds__(128) void k_scanpart(const int* __restrict__ part,
        int* __restrict__ boff, int* __restrict__ rowptr) {
    __shared__ int buf[128];
    int li = threadIdx.x;
    int v = (li < PBLK) ? part[li] : 0;
    buf[li] = v;
    __syncthreads();
    for (int off = 1; off < 128; off <<= 1) {
        int u = (li >= off) ? buf[li - off] : 0;
        __syncthreads();
        buf[li] += u;
        __syncthreads();
    }
    if (li < PBLK) boff[li] = buf[li] - v;
    if (li == 0) rowptr[N_NODES] = E_EDGES;
}

__global__ __launch_bounds__(1024) void k_rowfill(const int* __restrict__ deg,
        const int* __restrict__ boff, int* __restrict__ rowptr,
        int* __restrict__ cursor, float* __restrict__ inv) {
    __shared__ int buf[1024];
    int li = threadIdx.x;
    int gid = blockIdx.x * 1024 + li;
    int d = (gid < N_NODES) ? deg[gid] : 0;
    buf[li] = d;
    __syncthreads();
    for (int off = 1; off < 1024; off <<= 1) {
        int u = (li >= off) ? buf[li - off] : 0;
        __syncthreads();
        buf[li] += u;
        __syncthreads();
    }
    if (gid < N_NODES) {
        int excl = boff[blockIdx.x] + buf[li] - d;
        rowptr[gid] = excl;
        cursor[gid] = excl;
        inv[gid] = 1.0f / (float)(d > 1 ? d : 1);
    }
}

// ---------------- CSR fill ----------------
__global__ void k_fill(const int* __restrict__ ei, int* __restrict__ cursor,
                       int* __restrict__ csr_src) {
    int e = blockIdx.x * blockDim.x + threadIdx.x;
    if (e < E_EDGES) {
        int dst = ei[E_EDGES + e];
        int pos = atomicAdd(&cursor[dst], 1);
        csr_src[pos] = ei[e];
    }
}

// ---------------- edge-attr aggregation (t-invariant) ----------------
__global__ void k_agge(const int* __restrict__ ei, const float* __restrict__ ea,
                       float* __restrict__ agge) {
    int i = blockIdx.x * blockDim.x + threadIdx.x;   // over E*8
    if (i < E_EDGES * ED_DIM) {
        int e = i >> 3, j = i & 7;
        int dst = ei[E_EDGES + e];
        atomicAdd(&agge[dst * ED_DIM + j], ea[i]);
    }
}

__global__ void k_scale_agge(float* __restrict__ agge, const float* __restrict__ inv,
                             unsigned short* __restrict__ aggeb) {
    int i = blockIdx.x * blockDim.x + threadIdx.x;
    if (i < N_NODES * ED_DIM) {
        float v = agge[i] * inv[i >> 3];
        agge[i] = v;
        aggeb[i] = fbs(v);
    }
}

// ---------------- pack stats weights into MFMA B-frag layout, bf16 ----------------
__global__ void k_wprep(const float* __restrict__ wself, const float* __restrict__ wmsg,
                        unsigned short* __restrict__ wB) {
    int i = blockIdx.x * blockDim.x + threadIdx.x;   // over 5*4096 = 20480
    if (i < 20480) {
        int j = i & 7, q = (i >> 3) & 3, n = (i >> 5) & 127, kt = i >> 12;
        int k = kt * 32 + q * 8 + j;
        float v = 0.f;
        if (k < 64)       v = wself[k * 128 + n];
        else if (k < 136) v = wmsg[(k - 64) * 128 + n];
        wB[i] = fbs(v);
    }
}

// ---------------- pack LSTM weights, gate-permuted MFMA B-frag layout, bf16 ----------------
__global__ void k_wlstm(const float* __restrict__ wih, const float* __restrict__ whh,
                        unsigned short* __restrict__ wL) {
    int i = blockIdx.x * blockDim.x + threadIdx.x;   // over 8*512*32 = 131072
    if (i < 131072) {
        int j8 = i & 7, q = (i >> 3) & 3, np = (i >> 5) & 511, kt = i >> 14;
        int k = kt * 32 + q * 8 + j8;
        int hsub = np >> 6, gate = (np >> 4) & 3, hlo = np & 15;
        int j = gate * 128 + hsub * 16 + hlo;
        float v = (k < 128) ? wih[j * H_DIM + k] : whh[j * H_DIM + (k - 128)];
        wL[i] = fbs(v);
    }
}

// ---------------- fused all-t CSR gather: aggxb[n][t*64+f] = inv[n]*sum x[src][t*64+f] ----------------
// one wave per node; walks CSR ONCE; per edge loads the full 1280-B row (all 10 t);
// lane owns 5 uints (10 bf16 features) spread at 256-B stride -> coalesced chunks.
// 2-edge unroll => 10 loads in flight per lane.
__global__ __launch_bounds__(256) void k_gather_all(const unsigned short* __restrict__ xb,
        const int* __restrict__ rowptr, const int* __restrict__ csr_src,
        const float* __restrict__ inv, unsigned short* __restrict__ aggxb) {
    int node = blockIdx.x * 4 + (threadIdx.x >> 6);
    int lane = threadIdx.x & 63;
    int beg = rowptr[node], end = rowptr[node + 1];
    float a[10];
    #pragma unroll
    for (int c = 0; c < 10; c++) a[c] = 0.f;
    const unsigned int* xbu = (const unsigned int*)xb;
    int e = beg;
    for (; e + 1 < end; e += 2) {
        int s0 = csr_src[e], s1 = csr_src[e + 1];
        const unsigned int* r0 = xbu + (size_t)s0 * 320 + lane;
        const unsigned int* r1 = xbu + (size_t)s1 * 320 + lane;
        unsigned int u0[5], u1[5];
        #pragma unroll
        for (int c = 0; c < 5; c++) { u0[c] = r0[c * 64]; u1[c] = r1[c * 64]; }
        #pragma unroll
        for (int c = 0; c < 5; c++) {
            a[2 * c]     += __uint_as_float(u0[c] << 16) + __uint_as_float(u1[c] << 16);
            a[2 * c + 1] += __uint_as_float(u0[c] & 0xffff0000u)
                          + __uint_as_float(u1[c] & 0xffff0000u);
        }
    }
    if (e < end) {
        int s0 = csr_src[e];
        const unsigned int* r0 = xbu + (size_t)s0 * 320 + lane;
        #pragma unroll
        for (int c = 0; c < 5; c++) {
            unsigned int u = r0[c * 64];
            a[2 * c]     += __uint_as_float(u << 16);
            a[2 * c + 1] += __uint_as_float(u & 0xffff0000u);
        }
    }
    float iv = inv[node];
    unsigned int* orow = (unsigned int*)aggxb + (size_t)node * 320 + lane;
    #pragma unroll
    for (int c = 0; c < 5; c++)
        orow[c * 64] = pack2(a[2 * c] * iv, a[2 * c + 1] * iv);
}

// ---------------- fused all-t BN stats via bf16 MFMA ----------------
// grid-stride over 32-row tiles; t-loop unrolled inside; per-t (cs,cq) in registers
// across all tiles; single atomic flush per block at the end.
__global__ __launch_bounds__(256) void k_stats_all(const unsigned short* __restrict__ xb,
        const unsigned short* __restrict__ aggxb, const unsigned short* __restrict__ aggeb,
        const unsigned short* __restrict__ wB, float* __restrict__ sums) {
    __shared__ __align__(16) unsigned short s_xa[32 * XROW];
    int tid  = threadIdx.x;
    int wave = tid >> 6, lane = tid & 63;
    int q = lane >> 4, m = lane & 15;
    int n0 = wave * 32;

    short8 bf[5][2];
    #pragma unroll
    for (int kt = 0; kt < 5; kt++) {
        bf[kt][0] = *(const short8*)&wB[kt * 4096 + (n0 + m) * 32 + q * 8];
        bf[kt][1] = *(const short8*)&wB[kt * 4096 + (n0 + 16 + m) * 32 + q * 8];
    }

    float cs[T_STEPS][2], cq[T_STEPS][2];
    #pragma unroll
    for (int t = 0; t < T_STEPS; t++) {
        cs[t][0] = cs[t][1] = 0.f;
        cq[t][0] = cq[t][1] = 0.f;
    }

    for (int tile = blockIdx.x; tile < N_NODES / 32; tile += gridDim.x) {
        int row0 = tile * 32;
        #pragma unroll
        for (int t = 0; t < T_STEPS; t++) {
            __syncthreads();   // previous t's LDS reads done before restage
            for (int i = tid; i < 32 * 20; i += 256) {
                int r = i / 20, qq = i - r * 20;
                int n = row0 + r;
                uint4 v = make_uint4(0, 0, 0, 0);
                if (qq < 8)        v = *(const uint4*)&xb[(size_t)n * TF + t * F_DIM + qq * 8];
                else if (qq < 16)  v = *(const uint4*)&aggxb[(size_t)n * TF + t * F_DIM + (qq - 8) * 8];
                else if (qq == 16) v = *(const uint4*)&aggeb[n * ED_DIM];
                *(uint4*)&s_xa[r * XROW + qq * 8] = v;
            }
            __syncthreads();

            f32x4 a00 = {0.f,0.f,0.f,0.f}, a01 = a00, a10 = a00, a11 = a00;
            #pragma unroll
            for (int kt = 0; kt < 5; kt++) {
                short8 af0 = *(const short8*)&s_xa[m * XROW + kt * 32 + q * 8];
                short8 af1 = *(const short8*)&s_xa[(16 + m) * XROW + kt * 32 + q * 8];
                a00 = __builtin_amdgcn_mfma_f32_16x16x32_bf16(af0, bf[kt][0], a00, 0, 0, 0);
                a10 = __builtin_amdgcn_mfma_f32_16x16x32_bf16(af1, bf[kt][0], a10, 0, 0, 0);
                a01 = __builtin_amdgcn_mfma_f32_16x16x32_bf16(af0, bf[kt][1], a01, 0, 0, 0);
                a11 = __builtin_amdgcn_mfma_f32_16x16x32_bf16(af1, bf[kt][1], a11, 0, 0, 0);
            }
            #pragma unroll
            for (int g = 0; g < 4; g++) {
                float v0 = a00[g], v1 = a10[g];
                cs[t][0] += v0 + v1;
                cq[t][0] += v0 * v0 + v1 * v1;
                float w0 = a01[g], w1 = a11[g];
                cs[t][1] += w0 + w1;
                cq[t][1] += w0 * w0 + w1 * w1;
            }
        }
    }

    #pragma unroll
    for (int t = 0; t < T_STEPS; t++) {
        float cs0 = cs[t][0], cq0 = cq[t][0], cs1 = cs[t][1], cq1 = cq[t][1];
        cs0 += __shfl_xor(cs0, 16, 64); cq0 += __shfl_xor(cq0, 16, 64);
        cs0 += __shfl_xor(cs0, 32, 64); cq0 += __shfl_xor(cq0, 32, 64);
        cs1 += __shfl_xor(cs1, 16, 64); cq1 += __shfl_xor(cq1, 16, 64);
        cs1 += __shfl_xor(cs1, 32, 64); cq1 += __shfl_xor(cq1, 32, 64);
        if (lane < 16) {
            float* st = sums + t * 256;
            atomicAdd(&st[n0 + m], cs0);
            atomicAdd(&st[128 + n0 + m], cq0);
            atomicAdd(&st[n0 + 16 + m], cs1);
            atomicAdd(&st[128 + n0 + 16 + m], cq1);
        }
    }
}

// ---------------- fused all-t focal rows ----------------
__global__ __launch_bounds__(128) void k_focal_all(const float* __restrict__ x,
        const unsigned short* __restrict__ aggxb, const float* __restrict__ agge,
        const float* __restrict__ wself, const float* __restrict__ wmsg,
        const float* __restrict__ sums, const float* __restrict__ gamma,
        const float* __restrict__ beta, const int* __restrict__ ptr,
        unsigned short* __restrict__ hseqb) {
    __shared__ float s_xin[K_IN];
    int b   = blockIdx.x;
    int n   = ptr[b];
    int tid = threadIdx.x;
    int h = tid;
    float gm = gamma[h], bt = beta[h];
    for (int t = 0; t < T_STEPS; t++) {
        __syncthreads();   // previous t's s_xin reads done
        if (tid < K_IN - 64) {
            int k = 64 + tid;
            s_xin[k] = (k < 128) ? bs2f(aggxb[(size_t)n * TF + t * F_DIM + (k - 64)])
                                 : agge[n * ED_DIM + (k - 128)];
        }
        {
            int k = tid & 63;
            s_xin[k] = x[(size_t)n * TF + t * F_DIM + k];
        }
        __syncthreads();
        float acc = 0.f;
        #pragma unroll 8
        for (int k = 0; k < F_DIM; k++) acc += s_xin[k] * wself[k * H_DIM + h];
        #pragma unroll 8
        for (int k = 0; k < 72; k++)    acc += s_xin[F_DIM + k] * wmsg[k * H_DIM + h];
        const float* st = sums + t * 256;
        float mean = st[h] * (1.0f / N_NODES);
        float var  = st[H_DIM + h] * (1.0f / N_NODES) - mean * mean;
        var = fmaxf(var, 0.f);
        float istd = 1.0f / sqrtf(var + 1e-5f);
        float sc = gm * istd;
        float sh = bt - mean * sc;
        float v = fmaxf(acc * sc + sh, 0.f);
        hseqb[(size_t)(t * B_BATCH + b) * H_DIM + h] = fbs(v);
    }
}

// ---------------- persistent MFMA LSTM: all 10 steps in one kernel ----------------
// 128 blocks x 512 thr; block owns 16 rows; wave owns 64 gate-cols (full i,f,g,o
// for 16 h-dims); wL hoisted into 128 VGPRs (t-invariant); LDS pitch 136 bf16.
__global__ __launch_bounds__(512) void k_lstm_all(const unsigned short* __restrict__ hseqb,
        const unsigned short* __restrict__ wL, const float* __restrict__ bih,
        const float* __restrict__ bhh, float* __restrict__ hn) {
    __shared__ __align__(16) unsigned short s_hin[16 * LPITCH];
    __shared__ __align__(16) unsigned short s_h[16 * LPITCH];
    int tid = threadIdx.x, w = tid >> 6, lane = tid & 63;
    int q = lane >> 4, hlo = lane & 15;
    int row0 = blockIdx.x * 16;
    for (int i = tid; i < 16 * LPITCH / 8; i += 512)
        ((uint4*)s_h)[i] = make_uint4(0, 0, 0, 0);
    float c[4] = {0.f, 0.f, 0.f, 0.f};
    float bias[4];
    #pragma unroll
    for (int nt = 0; nt < 4; nt++) {
        int j = nt * 128 + w * 16 + hlo;
        bias[nt] = bih[j] + bhh[j];
    }
    short8 bfr[8][4];
    #pragma unroll
    for (int kt = 0; kt < 8; kt++)
        #pragma unroll
        for (int nt = 0; nt < 4; nt++)
            bfr[kt][nt] = *(const short8*)&wL[((kt * 512) + (w * 64 + nt * 16 + hlo)) * 32 + q * 8];

    for (int t = 0; t < T_STEPS; t++) {
        if (tid < 256) {
            int r = tid >> 4, cc = tid & 15;
            ((uint4*)&s_hin[r * LPITCH])[cc] =
                ((const uint4*)(hseqb + (size_t)(t * B_BATCH + row0 + r) * H_DIM))[cc];
        }
        __syncthreads();   // s_hin staged; prev-iter s_h writes visible
        f32x4 acc[4];
        #pragma unroll
        for (int nt = 0; nt < 4; nt++) acc[nt] = (f32x4){0.f, 0.f, 0.f, 0.f};
        #pragma unroll
        for (int kt = 0; kt < 8; kt++) {
            const unsigned short* abase = (kt < 4) ? s_hin : s_h;
            int ko = (kt & 3) * 32 + q * 8;
            short8 am = *(const short8*)&abase[hlo * LPITCH + ko];
            #pragma unroll
            for (int nt = 0; nt < 4; nt++)
                acc[nt] = __builtin_amdgcn_mfma_f32_16x16x32_bf16(am, bfr[kt][nt], acc[nt], 0, 0, 0);
        }
        __syncthreads();   // all s_h reads done before overwrite
        #pragma unroll
        for (int r = 0; r < 4; r++) {
            float gi = acc[0][r] + bias[0];
            float gf = acc[1][r] + bias[1];
            float gg = acc[2][r] + bias[2];
            float go = acc[3][r] + bias[3];
            float si = fsig(gi);
            float sf = fsig(gf);
            float so = fsig(go);
            float tg = ftanh(gg);
            float cn = sf * c[r] + si * tg;
            c[r] = cn;
            float hv = so * ftanh(cn);
            int row = q * 4 + r;
            s_h[row * LPITCH + w * 16 + hlo] = fbs(hv);
            if (t == T_STEPS - 1)
                hn[(size_t)(row0 + row) * H_DIM + w * 16 + hlo] = hv;
        }
    }
}

// ---------------- classifier ----------------
__global__ void k_cls(const float* __restrict__ h, const float* __restrict__ wcls,
                      const float* __restrict__ bcls, float* __restrict__ out) {
    int i = blockIdx.x * blockDim.x + threadIdx.x;
    if (i < B_BATCH * C_CLS) {
        int b = i >> 1, cc = i & 1;
        float acc = bcls[cc];
        for (int k = 0; k < H_DIM; k++) acc += h[b * H_DIM + k] * wcls[k * C_CLS + cc];
        out[i] = acc;
    }
}

extern "C" void kernel_launch(void* const* d_in, const int* in_sizes, int n_in,
                              void* d_out, int out_size, void* d_ws, size_t ws_size,
                              hipStream_t stream) {
    const float* x     = (const float*)d_in[0];
    const int*   ei    = (const int*)d_in[1];
    const float* ea    = (const float*)d_in[2];
    const int*   ptr   = (const int*)d_in[3];
    const float* wmsg  = (const float*)d_in[4];
    const float* wself = (const float*)d_in[6];
    const float* gamma = (const float*)d_in[8];
    const float* beta  = (const float*)d_in[9];
    const float* wih   = (const float*)d_in[10];
    const float* whh   = (const float*)d_in[11];
    const float* bih   = (const float*)d_in[12];
    const float* bhh   = (const float*)d_in[13];
    const float* wcls  = (const float*)d_in[14];
    const float* bcls  = (const float*)d_in[15];
    float* out = (float*)d_out;

    float* ws = (float*)d_ws;
    int*            deg    = (int*)(ws + WS_DEG);
    int*            rowptr = (int*)(ws + WS_ROWPTR);
    int*            cursor = (int*)(ws + WS_CURSOR);
    float*          inv    = ws + WS_INV;
    float*          agge   = ws + WS_AGGE;
    float*          sums   = ws + WS_SUMS;
    int*            csrs   = (int*)(ws + WS_CSRSRC);
    unsigned short* aggeb  = (unsigned short*)(ws + WS_AGGEB);
    unsigned short* hseqb  = (unsigned short*)(ws + WS_HSEQB);
    float*          hn     = ws + WS_HN;
    unsigned short* wB     = (unsigned short*)(ws + WS_WB);
    unsigned short* wL     = (unsigned short*)(ws + WS_WL);
    int*            part   = (int*)(ws + WS_PART);
    int*            boff   = (int*)(ws + WS_BOFF);
    unsigned short* xb     = (unsigned short*)(ws + WS_XB);
    unsigned short* aggxb  = (unsigned short*)(ws + WS_AGGXB);

    hipMemsetAsync(ws, 0, (size_t)WS_ZEND * 4, stream);

    k_xcast<<<31250, 256, 0, stream>>>(x, xb);
    k_deg<<<(E_EDGES + 255) / 256, 256, 0, stream>>>(ei, deg);
    k_part<<<PBLK, 1024, 0, stream>>>(deg, part);
    k_scanpart<<<1, 128, 0, stream>>>(part, boff, rowptr);
    k_rowfill<<<PBLK, 1024, 0, stream>>>(deg, boff, rowptr, cursor, inv);
    k_agge<<<(E_EDGES * ED_DIM + 255) / 256, 256, 0, stream>>>(ei, ea, agge);
    k_scale_agge<<<(N_NODES * ED_DIM + 255) / 256, 256, 0, stream>>>(agge, inv, aggeb);
    k_fill<<<(E_EDGES + 255) / 256, 256, 0, stream>>>(ei, cursor, csrs);
    k_wprep<<<80, 256, 0, stream>>>(wself, wmsg, wB);
    k_wlstm<<<512, 256, 0, stream>>>(wih, whh, wL);

    k_gather_all<<<N_NODES / 4, 256, 0, stream>>>(xb, rowptr, csrs, inv, aggxb);
    k_stats_all<<<512, 256, 0, stream>>>(xb, aggxb, aggeb, wB, sums);
    k_focal_all<<<B_BATCH, 128, 0, stream>>>(x, aggxb, agge, wself, wmsg, sums,
                                             gamma, beta, ptr, hseqb);
    k_lstm_all<<<B_BATCH / 16, 512, 0, stream>>>(hseqb, wL, bih, bhh, hn);
    k_cls<<<(B_BATCH * C_CLS + 255) / 256, 256, 0, stream>>>(hn, wcls, bcls, out);
}